// Round 2
// baseline (383.997 us; speedup 1.0000x reference)
//
#include <hip/hip_runtime.h>

#define B_    4
#define NPTS  4096
#define NUP   16384
#define CH    64
#define TILE  2048
#define QPB   64

// ---------------------------------------------------------------------------
// Kernel 1: brute-force top-3 nearest neighbors + normalized inverse-distance
// weights. 4 lanes per query, 4 independent top-3 chains per lane (ILP),
// pos staged in LDS as (x,y,z,|p|^2) float4 tiles.
// ---------------------------------------------------------------------------
__global__ __launch_bounds__(256, 4) void knn3_kernel(
    const float* __restrict__ pos,      // [B][NPTS][3]
    const float* __restrict__ pos_up,   // [B][NUP][3]
    int* __restrict__ out_idx,          // [B][NUP][3]
    float* __restrict__ out_w)          // [B][NUP][3]
{
    __shared__ float4 sp[TILE];
    const int t  = threadIdx.x;
    const int s  = t & 3;          // subset lane within query group
    const int qi = t >> 2;         // query within block
    const int b     = blockIdx.x >> 8;            // / (NUP/QPB)
    const int qbase = (blockIdx.x & 255) * QPB;
    const int q     = qbase + qi;

    const float* pu = pos_up + ((size_t)b * NUP + q) * 3;
    const float qx = pu[0], qy = pu[1], qz = pu[2];
    const float q2 = qx * qx + qy * qy + qz * qz;

    // 4 independent sorted top-3 chains (d0<=d1<=d2) of d_eff = |p|^2 - 2 q.p
    float d0[4], d1[4], d2[4];
    int   i0[4], i1[4], i2[4];
#pragma unroll
    for (int u = 0; u < 4; ++u) {
        d0[u] = d1[u] = d2[u] = 3.4e38f;
        i0[u] = i1[u] = i2[u] = 0;
    }

    const float* pb = pos + (size_t)b * NPTS * 3;

    for (int tile = 0; tile < NPTS; tile += TILE) {
        __syncthreads();
        // cooperative stage: 2048 points, 256 threads -> 8 each
        for (int j = t; j < TILE; j += 256) {
            const float* p = pb + (size_t)(tile + j) * 3;
            const float x = p[0], y = p[1], z = p[2];
            sp[j] = make_float4(x, y, z, x * x + y * y + z * z);
        }
        __syncthreads();
        // lane s scans j = s + 16*i + 4*u : at fixed (i,u) the wave touches 4
        // consecutive float4s (16B apart) -> conflict-free broadcast
#pragma unroll 2
        for (int i = 0; i < TILE / 16; ++i) {
#pragma unroll
            for (int u = 0; u < 4; ++u) {
                const int j = s + 16 * i + 4 * u;
                const float4 p = sp[j];
                const float dot = qx * p.x + qy * p.y + qz * p.z;
                const float de  = __builtin_fmaf(-2.f, dot, p.w);
                if (__builtin_expect(de < d2[u], 0)) {   // rare insert
                    const int jj = tile + j;
                    const bool lt1 = de < d1[u], lt0 = de < d0[u];
                    d2[u] = lt1 ? d1[u] : de;            i2[u] = lt1 ? i1[u] : jj;
                    d1[u] = lt1 ? (lt0 ? d0[u] : de) : d1[u];
                    i1[u] = lt1 ? (lt0 ? i0[u] : jj) : i1[u];
                    d0[u] = lt0 ? de : d0[u];            i0[u] = lt0 ? jj : i0[u];
                }
            }
        }
    }

    // merge the 4 chains into chain 0's triple
    float D0 = d0[0], D1 = d1[0], D2 = d2[0];
    int   I0 = i0[0], I1 = i1[0], I2 = i2[0];
    auto ins = [&](float d, int j) {
        if (d < D2) {
            const bool lt1 = d < D1, lt0 = d < D0;
            D2 = lt1 ? D1 : d;               I2 = lt1 ? I1 : j;
            D1 = lt1 ? (lt0 ? D0 : d) : D1;  I1 = lt1 ? (lt0 ? I0 : j) : I1;
            D0 = lt0 ? d : D0;               I0 = lt0 ? j : I0;
        }
    };
#pragma unroll
    for (int u = 1; u < 4; ++u) {
        ins(d0[u], i0[u]); ins(d1[u], i1[u]); ins(d2[u], i2[u]);
    }
    // merge across the 4 subset lanes (butterfly)
#pragma unroll
    for (int m = 1; m <= 2; m <<= 1) {
        const float e0 = __shfl_xor(D0, m), e1 = __shfl_xor(D1, m), e2 = __shfl_xor(D2, m);
        const int   j0 = __shfl_xor(I0, m), j1 = __shfl_xor(I1, m), j2 = __shfl_xor(I2, m);
        ins(e0, j0); ins(e1, j1); ins(e2, j2);
    }

    if (s == 0) {
        const float w0 = 1.f / (D0 + q2 + 1e-6f);   // restore true d^2
        const float w1 = 1.f / (D1 + q2 + 1e-6f);
        const float w2 = 1.f / (D2 + q2 + 1e-6f);
        const float inv = 1.f / (w0 + w1 + w2);
        const size_t o = ((size_t)b * NUP + q) * 3;
        out_idx[o]     = I0; out_idx[o + 1] = I1; out_idx[o + 2] = I2;
        out_w[o]       = w0 * inv;
        out_w[o + 1]   = w1 * inv;
        out_w[o + 2]   = w2 * inv;
    }
}

// ---------------------------------------------------------------------------
// Kernel 2: gather 3 feature rows, blend with weights, 64x64 matvec + bias +
// ReLU. 2 threads per query (h = output half), nf[64] kept in registers
// (constant indexing only), W read via L1-resident wave-uniform loads.
// ---------------------------------------------------------------------------
__global__ __launch_bounds__(256) void interp_kernel(
    const float* __restrict__ F,        // [B][NPTS][CH]
    const int* __restrict__ idx,        // [B*NUP][3]
    const float* __restrict__ wgt,      // [B*NUP][3]
    const float* __restrict__ W,        // [CH][CH]
    const float* __restrict__ bias,     // [CH]
    float* __restrict__ out)            // [B*NUP][CH]
{
    const int id = blockIdx.x * 256 + threadIdx.x;   // 0 .. 2*B*NUP-1
    const int q  = id >> 1;
    const int h  = id & 1;
    const int b  = q >> 14;                          // / NUP
    const float* Fb = F + (size_t)b * NPTS * CH;
    const size_t o3 = (size_t)q * 3;
    const int   i0 = idx[o3], i1 = idx[o3 + 1], i2 = idx[o3 + 2];
    const float w0 = wgt[o3], w1 = wgt[o3 + 1], w2 = wgt[o3 + 2];
    const float4* f0 = (const float4*)(Fb + (size_t)i0 * CH);
    const float4* f1 = (const float4*)(Fb + (size_t)i1 * CH);
    const float4* f2 = (const float4*)(Fb + (size_t)i2 * CH);

    float nf[CH];
#pragma unroll
    for (int c4 = 0; c4 < 16; ++c4) {
        const float4 a = f0[c4], e = f1[c4], g = f2[c4];
        nf[4 * c4 + 0] = w0 * a.x + w1 * e.x + w2 * g.x;
        nf[4 * c4 + 1] = w0 * a.y + w1 * e.y + w2 * g.y;
        nf[4 * c4 + 2] = w0 * a.z + w1 * e.z + w2 * g.z;
        nf[4 * c4 + 3] = w0 * a.w + w1 * e.w + w2 * g.w;
    }

    const float4* W4 = (const float4*)W;     // [CH][16]
    const float4* b4 = (const float4*)bias;  // [16]
    float4* o4 = (float4*)(out + (size_t)q * CH) + h * 8;
#pragma unroll 1
    for (int j = 0; j < 8; ++j) {
        const int col = h * 8 + j;
        float4 acc = b4[col];
#pragma unroll
        for (int c = 0; c < CH; ++c) {
            const float4 wv = W4[c * 16 + col];
            acc.x = __builtin_fmaf(nf[c], wv.x, acc.x);
            acc.y = __builtin_fmaf(nf[c], wv.y, acc.y);
            acc.z = __builtin_fmaf(nf[c], wv.z, acc.z);
            acc.w = __builtin_fmaf(nf[c], wv.w, acc.w);
        }
        acc.x = fmaxf(acc.x, 0.f);
        acc.y = fmaxf(acc.y, 0.f);
        acc.z = fmaxf(acc.z, 0.f);
        acc.w = fmaxf(acc.w, 0.f);
        o4[j] = acc;
    }
}

extern "C" void kernel_launch(void* const* d_in, const int* in_sizes, int n_in,
                              void* d_out, int out_size, void* d_ws, size_t ws_size,
                              hipStream_t stream)
{
    const float* feature = (const float*)d_in[0];
    const float* pos     = (const float*)d_in[1];
    const float* pos_up  = (const float*)d_in[2];
    const float* W       = (const float*)d_in[3];
    const float* bias    = (const float*)d_in[4];
    float* out = (float*)d_out;

    int*   idx = (int*)d_ws;                                            // B*NUP*3 ints
    float* wgt = (float*)((char*)d_ws + (size_t)B_ * NUP * 3 * sizeof(int));

    knn3_kernel<<<dim3(B_ * (NUP / QPB)), dim3(256), 0, stream>>>(pos, pos_up, idx, wgt);
    interp_kernel<<<dim3(B_ * NUP * 2 / 256), dim3(256), 0, stream>>>(feature, idx, wgt, W, bias, out);
}

// Round 12
// 250.870 us; speedup vs baseline: 1.5307x; 1.5307x over previous
//
#include <hip/hip_runtime.h>

#define B_    4
#define NPTS  4096
#define NUP   16384
#define CH    64

// branchless sorted-triple insert with indices: 3 v_cmp + 6 v_cndmask
#define INSI(D0,D1,D2,I0,I1,I2,DV,JV) { float _d=(DV); int _j=(JV); \
    bool _l0=_d<D0, _l1=_d<D1, _l2=_d<D2; \
    float _n2=_l1?D1:(_l2?_d:D2); int _m2=_l1?I1:(_l2?_j:I2); \
    float _n1=_l0?D0:(_l1?_d:D1); int _m1=_l0?I0:(_l1?_j:I1); \
    float _n0=_l0?_d:D0;          int _m0=_l0?_j:I0; \
    D0=_n0;D1=_n1;D2=_n2; I0=_m0;I1=_m1;I2=_m2; }

// ---------------------------------------------------------------------------
// kNN top-3: exact fp32, ONE pass (d,idx inserted together -> no cross-pass
// rounding hazard). Block = 256 thr, LDS = whole 4096-pt cloud (x,y,z,|p|^2).
// Wave: 8 query-slots x 8 subset-lanes; each lane owns 4 queries, scans
// j = s + 8*i (8 broadcast ds_read_b128 lines, conflict-free).
// Semantics identical to the R2-proven kernel (same formula, same weights).
// ---------------------------------------------------------------------------
__global__ __launch_bounds__(256, 2) void knn_onepass(
    const float* __restrict__ pos,
    const float* __restrict__ pos_up,
    int* __restrict__ out_idx,       // [B*NUP][3]
    float* __restrict__ out_w)       // [B*NUP][3]
{
    __shared__ float4 sp[NPTS];                 // 64 KB
    const int t = threadIdx.x;
    const int b = blockIdx.x >> 7;
    const int qchunk = (blockIdx.x & 127) * 128;

    const float* pb = pos + (size_t)b * NPTS * 3;
    for (int j = t; j < NPTS; j += 256) {
        const float x = pb[3*j], y = pb[3*j+1], z = pb[3*j+2];
        sp[j] = make_float4(x, y, z, x*x + y*y + z*z);
    }
    __syncthreads();

    const int l = t & 63;
    const int s = l & 7, slot = l >> 3;
    const int wv = t >> 6;
    const int q0 = qchunk + wv * 32 + slot * 4;

    float qx[4], qy[4], qz[4];
#pragma unroll
    for (int m = 0; m < 4; ++m) {
        const float* pu = pos_up + ((size_t)b * NUP + q0 + m) * 3;
        qx[m] = pu[0]; qy[m] = pu[1]; qz[m] = pu[2];
    }

    float D0[4], D1[4], D2[4];
    int   I0[4], I1[4], I2[4];
#pragma unroll
    for (int m = 0; m < 4; ++m) {
        D0[m]=3.4e38f; D1[m]=3.4e38f; D2[m]=3.4e38f;
        I0[m]=0; I1[m]=0; I2[m]=0;
    }

#pragma unroll 2
    for (int i = 0; i < NPTS/8; ++i) {
        const int j = s + 8*i;
        const float4 p = sp[j];
#pragma unroll
        for (int m = 0; m < 4; ++m) {
            const float dot = qx[m]*p.x + qy[m]*p.y + qz[m]*p.z;
            const float de  = __builtin_fmaf(-2.f, dot, p.w);   // |p|^2 - 2 q.p
            INSI(D0[m],D1[m],D2[m], I0[m],I1[m],I2[m], de, j);
        }
    }

    // butterfly merge across the 8 subset lanes (XOR masks stay in s-group)
#pragma unroll
    for (int mk = 1; mk <= 4; mk <<= 1) {
#pragma unroll
        for (int m = 0; m < 4; ++m) {
            const float e0=__shfl_xor(D0[m],mk), e1=__shfl_xor(D1[m],mk), e2=__shfl_xor(D2[m],mk);
            const int   j0=__shfl_xor(I0[m],mk), j1=__shfl_xor(I1[m],mk), j2=__shfl_xor(I2[m],mk);
            INSI(D0[m],D1[m],D2[m], I0[m],I1[m],I2[m], e0, j0);
            INSI(D0[m],D1[m],D2[m], I0[m],I1[m],I2[m], e1, j1);
            INSI(D0[m],D1[m],D2[m], I0[m],I1[m],I2[m], e2, j2);
        }
    }

    if (s == 0) {
#pragma unroll
        for (int m = 0; m < 4; ++m) {
            const float q2 = qx[m]*qx[m] + qy[m]*qy[m] + qz[m]*qz[m];
            const float w0 = 1.f / (D0[m] + q2 + 1e-6f);
            const float w1 = 1.f / (D1[m] + q2 + 1e-6f);
            const float w2 = 1.f / (D2[m] + q2 + 1e-6f);
            const float inv = 1.f / (w0 + w1 + w2);
            const size_t o = ((size_t)b * NUP + q0 + m) * 3;
            out_idx[o]   = I0[m] & 4095;
            out_idx[o+1] = I1[m] & 4095;
            out_idx[o+2] = I2[m] & 4095;
            out_w[o]   = w0 * inv;
            out_w[o+1] = w1 * inv;
            out_w[o+2] = w2 * inv;
        }
    }
}

// ---------------------------------------------------------------------------
// interp: gather+blend with knn-provided weights (4 lanes/query, coalesced),
// 64x64 matvec with W in LDS; each lane computes 4 queries x 4 cols.
// Math identical to R2's proven interp; only the parallel decomposition
// differs.
// ---------------------------------------------------------------------------
__global__ __launch_bounds__(256) void interp_g4(
    const float* __restrict__ F,
    const int* __restrict__ idx,
    const float* __restrict__ wgt,
    const float* __restrict__ W,
    const float* __restrict__ bias,
    float* __restrict__ out)
{
    __shared__ float  Wl[CH * CH];       // 16 KB
    __shared__ float4 nfl[64][17];       // padded rows
    const int t = threadIdx.x;
    const int qblk = blockIdx.x * 64;

    {   // stage W
        const float4* W4 = (const float4*)W;
        float4* Wl4 = (float4*)Wl;
#pragma unroll
        for (int i = 0; i < 4; ++i) Wl4[t + i * 256] = W4[t + i * 256];
    }
    {   // blend
        const int ql = t >> 2, r4 = t & 3;
        const int q = qblk + ql;
        const int bb = q >> 14;
        const float* Fb = F + (size_t)bb * NPTS * CH;
        const size_t o3 = (size_t)q * 3;
        const int   i0 = idx[o3], i1 = idx[o3+1], i2 = idx[o3+2];
        const float w0 = wgt[o3], w1 = wgt[o3+1], w2 = wgt[o3+2];
        const float4* f0 = (const float4*)(Fb + (size_t)i0 * CH);
        const float4* f1 = (const float4*)(Fb + (size_t)i1 * CH);
        const float4* f2 = (const float4*)(Fb + (size_t)i2 * CH);
#pragma unroll
        for (int jj = 0; jj < 4; ++jj) {
            const int c4 = jj * 4 + r4;
            const float4 a = f0[c4], e = f1[c4], h = f2[c4];
            float4 nf;
            nf.x = w0*a.x + w1*e.x + w2*h.x;
            nf.y = w0*a.y + w1*e.y + w2*h.y;
            nf.z = w0*a.z + w1*e.z + w2*h.z;
            nf.w = w0*a.w + w1*e.w + w2*h.w;
            nfl[ql][c4] = nf;
        }
    }
    __syncthreads();
    {   // matvec
        const int wv = t >> 6, l = t & 63;
        const int cb = wv * 4 + (l & 3);        // float4 column block, 0..15
        const int qq = (l >> 2) * 4;            // local query base, 0..60
        const float4* b4 = (const float4*)bias;
        const float4  bv = b4[cb];
        float4 ac0 = bv, ac1 = bv, ac2 = bv, ac3 = bv;
        const float4* Wl4 = (const float4*)Wl;
#pragma unroll
        for (int c4 = 0; c4 < 16; ++c4) {
            const float4 n0 = nfl[qq+0][c4];
            const float4 n1 = nfl[qq+1][c4];
            const float4 n2 = nfl[qq+2][c4];
            const float4 n3 = nfl[qq+3][c4];
#pragma unroll
            for (int j = 0; j < 4; ++j) {
                const float4 wv4 = Wl4[(c4 * 4 + j) * 16 + cb];
                const float s0 = ((const float*)&n0)[j];
                const float s1 = ((const float*)&n1)[j];
                const float s2 = ((const float*)&n2)[j];
                const float s3 = ((const float*)&n3)[j];
                ac0.x = __builtin_fmaf(s0, wv4.x, ac0.x); ac0.y = __builtin_fmaf(s0, wv4.y, ac0.y);
                ac0.z = __builtin_fmaf(s0, wv4.z, ac0.z); ac0.w = __builtin_fmaf(s0, wv4.w, ac0.w);
                ac1.x = __builtin_fmaf(s1, wv4.x, ac1.x); ac1.y = __builtin_fmaf(s1, wv4.y, ac1.y);
                ac1.z = __builtin_fmaf(s1, wv4.z, ac1.z); ac1.w = __builtin_fmaf(s1, wv4.w, ac1.w);
                ac2.x = __builtin_fmaf(s2, wv4.x, ac2.x); ac2.y = __builtin_fmaf(s2, wv4.y, ac2.y);
                ac2.z = __builtin_fmaf(s2, wv4.z, ac2.z); ac2.w = __builtin_fmaf(s2, wv4.w, ac2.w);
                ac3.x = __builtin_fmaf(s3, wv4.x, ac3.x); ac3.y = __builtin_fmaf(s3, wv4.y, ac3.y);
                ac3.z = __builtin_fmaf(s3, wv4.z, ac3.z); ac3.w = __builtin_fmaf(s3, wv4.w, ac3.w);
            }
        }
        float4* o4 = (float4*)out;
        const size_t q0 = (size_t)(qblk + qq);
#define RELU4(v) { v.x=fmaxf(v.x,0.f); v.y=fmaxf(v.y,0.f); v.z=fmaxf(v.z,0.f); v.w=fmaxf(v.w,0.f); }
        RELU4(ac0); RELU4(ac1); RELU4(ac2); RELU4(ac3);
        o4[(q0+0)*16 + cb] = ac0;
        o4[(q0+1)*16 + cb] = ac1;
        o4[(q0+2)*16 + cb] = ac2;
        o4[(q0+3)*16 + cb] = ac3;
    }
}

extern "C" void kernel_launch(void* const* d_in, const int* in_sizes, int n_in,
                              void* d_out, int out_size, void* d_ws, size_t ws_size,
                              hipStream_t stream)
{
    const float* feature = (const float*)d_in[0];
    const float* pos     = (const float*)d_in[1];
    const float* pos_up  = (const float*)d_in[2];
    const float* W       = (const float*)d_in[3];
    const float* bias    = (const float*)d_in[4];
    float* out = (float*)d_out;

    // ws layout == R2's proven 1.5 MB footprint
    int*   idxp = (int*)d_ws;                                            // 768 KB
    float* wgtp = (float*)((char*)d_ws + (size_t)B_ * NUP * 3 * sizeof(int));

    knn_onepass<<<dim3(512),  dim3(256), 0, stream>>>(pos, pos_up, idxp, wgtp);
    interp_g4  <<<dim3(1024), dim3(256), 0, stream>>>(feature, idxp, wgtp, W, bias, out);
}